// Round 1
// baseline (499.841 us; speedup 1.0000x reference)
//
#include <hip/hip_runtime.h>
#include <stdint.h>

#define Bb 8
#define Cc 256
#define Nn 2304
#define PQT 36   // proj: 64-token tiles
#define QTILES 36
#define KSPLIT 3
#define TPS 24   // 32-key tiles per split (72 total / KSPLIT)
#define L2E 1.44269504088896f

typedef unsigned short u16;
typedef _Float16 h16;
typedef h16  h16x8 __attribute__((ext_vector_type(8)));
typedef u16  u16x8 __attribute__((ext_vector_type(8)));
typedef float f32x4 __attribute__((ext_vector_type(4)));

static __device__ __forceinline__ u16 f2h(float f) {
  return __builtin_bit_cast(u16, (h16)f);
}
static __device__ __forceinline__ h16x8 ash(u16x8 v) {
  return __builtin_bit_cast(h16x8, v);
}
static __device__ __forceinline__ f32x4 mfma16(u16x8 a, u16x8 b, f32x4 c) {
  return __builtin_amdgcn_mfma_f32_16x16x32_f16(ash(a), ash(b), c, 0, 0, 0);
}

// DPP row_ror reductions over 16 lanes (VALU pipe)
template <int CTRL>
static __device__ __forceinline__ float dppmov(float x) {
  return __builtin_bit_cast(float,
      __builtin_amdgcn_mov_dpp(__builtin_bit_cast(int, x), CTRL, 0xF, 0xF, true));
}
static __device__ __forceinline__ float rowmax16(float x) {
  x = fmaxf(x, dppmov<0x121>(x));
  x = fmaxf(x, dppmov<0x122>(x));
  x = fmaxf(x, dppmov<0x124>(x));
  x = fmaxf(x, dppmov<0x128>(x));
  return x;
}
static __device__ __forceinline__ float rowsum16(float x) {
  x += dppmov<0x121>(x);
  x += dppmov<0x122>(x);
  x += dppmov<0x124>(x);
  x += dppmov<0x128>(x);
  return x;
}

// ---------------------------------------------------------------------------
// Prep: Wq,Wk,Wv fp32 [C][C] -> fp16 Wf [3][C*C].
// ---------------------------------------------------------------------------
__global__ void prep_kernel(const float* __restrict__ Wq,
                            const float* __restrict__ Wk,
                            const float* __restrict__ Wv,
                            u16* __restrict__ Wf)
{
  const int tid = blockIdx.x * 256 + threadIdx.x;
  const int m   = tid >> 13;
  const int off = (tid & 8191) * 8;
  const float* src = (m == 0) ? Wq : (m == 1) ? Wk : Wv;
  const f32x4 a = *(const f32x4*)(src + off);
  const f32x4 c = *(const f32x4*)(src + off + 4);
  u16x8 o;
#pragma unroll
  for (int j = 0; j < 4; ++j) { o[j] = f2h(a[j]); o[j + 4] = f2h(c[j]); }
  *(u16x8*)(Wf + (size_t)m * 65536 + off) = o;
}

// ---------------------------------------------------------------------------
// Projection v6 (all fp16, 1-term). W staged 32 full rows at a time in LDS
// (coalesced 512B row loads, XOR-swizzled b128 reads). z=0: Q [B][N][C],
// z=1: K [B][N][C], z=2: V^T [B][C][N]. grid (8,36,3), block 256.
// launch_bounds(256,4): 864 blocks all resident (16KB LDS), no tail gen.
// ---------------------------------------------------------------------------
__global__ __launch_bounds__(256, 4) void proj_kernel(
    const float* __restrict__ x, const float* __restrict__ y,
    const u16* __restrict__ Wf,
    const float* __restrict__ bq, const float* __restrict__ bk,
    const float* __restrict__ bv,
    u16* __restrict__ Qf, u16* __restrict__ Kf, u16* __restrict__ Vf)
{
  __shared__ u16 sW[32 * 256];   // 16 KB
  const int t    = threadIdx.x;
  const int b    = blockIdx.x;
  const int q0   = blockIdx.y * 64;
  const int z    = blockIdx.z;
  const int lane = t & 63;
  const int w    = t >> 6;
  const int quad = lane >> 4;
  const int l15  = lane & 15;

  const u16* WZ = Wf + (size_t)z * 65536;

  // token fragments (A for z<2, B for z==2): lane l15 -> token, k=quad*8+j
  const float* src = (z == 0) ? x : y;
  const int tok = q0 + w * 16 + l15;
  u16x8 af[8];
#pragma unroll
  for (int kc = 0; kc < 8; ++kc) {
    const float* p = src + ((size_t)b * Cc + kc * 32 + quad * 8) * Nn + tok;
    float v[8];
#pragma unroll
    for (int j = 0; j < 8; ++j) v[j] = p[(size_t)j * Nn];
#pragma unroll
    for (int j = 0; j < 8; ++j) af[kc][j] = f2h(v[j]);
  }

  f32x4 acc[16];
#pragma unroll
  for (int i = 0; i < 16; ++i) acc[i] = (f32x4){0.f, 0.f, 0.f, 0.f};

#pragma unroll 1
  for (int rg = 0; rg < 8; ++rg) {   // 32 c_out rows per round
    __syncthreads();
#pragma unroll
    for (int it = 0; it < 4; ++it) {
      const int id = it * 256 + t;
      const int row = id >> 5, gch = id & 31;
      const u16x8 v = *(const u16x8*)(WZ + (size_t)(rg * 32 + row) * 256 + gch * 8);
      *(u16x8*)(sW + row * 256 + ((gch ^ (row & 7)) << 3)) = v;
    }
    __syncthreads();
    if (z < 2) {
#pragma unroll
      for (int cbl = 0; cbl < 2; ++cbl) {
        const int rl = cbl * 16 + l15;
        f32x4 a = acc[rg * 2 + cbl];
#pragma unroll
        for (int kc = 0; kc < 8; ++kc) {
          const u16x8 bf = *(const u16x8*)(sW + rl * 256 + (((kc * 4 + quad) ^ (rl & 7)) << 3));
          a = mfma16(af[kc], bf, a);
        }
        acc[rg * 2 + cbl] = a;
      }
    } else {
#pragma unroll
      for (int mt = 0; mt < 2; ++mt) {
        const int rl = mt * 16 + l15;
        f32x4 a = acc[rg * 2 + mt];
#pragma unroll
        for (int kc = 0; kc < 8; ++kc) {
          const u16x8 wfr = *(const u16x8*)(sW + rl * 256 + (((kc * 4 + quad) ^ (rl & 7)) << 3));
          a = mfma16(wfr, af[kc], a);
        }
        acc[rg * 2 + mt] = a;
      }
    }
  }

  // epilogues
  if (z < 2) {
    const float* bias = (z == 0) ? bq : bk;
    u16* O = (z == 0) ? Qf : Kf;
#pragma unroll
    for (int cb = 0; cb < 16; ++cb) {
      const int co = cb * 16 + l15;
      const float bs = bias[co];
      const size_t base = ((size_t)b * Nn + q0 + w * 16 + quad * 4) * Cc + co;
#pragma unroll
      for (int r = 0; r < 4; ++r)
        O[base + (size_t)r * Cc] = f2h(acc[cb][r] + bs);
    }
  } else {
#pragma unroll
    for (int cb = 0; cb < 16; ++cb) {
      const int crow = cb * 16 + quad * 4;
#pragma unroll
      for (int r = 0; r < 4; ++r)
        Vf[((size_t)b * Cc + crow + r) * Nn + q0 + w * 16 + l15] =
            f2h(acc[cb][r] + bv[crow + r]);
    }
  }
}

// ---------------------------------------------------------------------------
// Flash attention v7: all fp16, 32-key tiles, register-prefetch pipeline.
// grid (8,36,KSPLIT=3) = 864 blocks, block 256 = 4 waves x 16 queries.
// LDS 36 KB, launch_bounds(256,4) -> 4 blocks/CU (144KB LDS, 84 VGPR): all
// 864 blocks resident in one generation (3.375/CU avg), occupancy ~42%.
// ---------------------------------------------------------------------------
__global__ __launch_bounds__(256, 4) void attn_kernel(
    const u16* __restrict__ Qf, const u16* __restrict__ Kf,
    const u16* __restrict__ Vf, float* __restrict__ Opart,
    float* __restrict__ Ml)
{
  __shared__ u16 sK[32 * 256];   // 16 KB
  __shared__ u16 sV[256 * 32];   // 16 KB
  __shared__ u16 sP[4 * 512];    //  4 KB
  const int t    = threadIdx.x;
  const int b    = blockIdx.x;
  const int q0   = blockIdx.y * 64;
  const int sp   = blockIdx.z;
  const int lane = t & 63;
  const int w    = t >> 6;
  const int quad = lane >> 4;
  const int l15  = lane & 15;

  // Q A-frags
  u16x8 qf[8];
  {
    const size_t qrow = ((size_t)b * Nn + q0 + w * 16 + l15) * Cc;
#pragma unroll
    for (int kc = 0; kc < 8; ++kc)
      qf[kc] = *(const u16x8*)(Qf + qrow + kc * 32 + quad * 8);
  }

  f32x4 o[16];
#pragma unroll
  for (int i = 0; i < 16; ++i) o[i] = (f32x4){0.f, 0.f, 0.f, 0.f};
  float mrow[4] = {-3e38f, -3e38f, -3e38f, -3e38f};
  float lrow[4] = {0.f, 0.f, 0.f, 0.f};

  const u16* Kb = Kf + (size_t)b * Nn * Cc;
  const u16* Vb = Vf + (size_t)b * Cc * Nn;
  const int gl = (l15 & 3) ^ ((l15 >> 2) & 3);

  // staging geometry (per-thread constants)
  const int krow = t >> 5;               // K: row 0..7 (+8*it)
  const int kch  = t & 31;               // K: global chunk (linear, coalesced)
  const int vc   = t >> 2;               // V: c row 0..63 (+64*it)
  const int vp   = t & 3;                // V: chunk

  u16x8 pk[4], pv[4];
  {
    const size_t kg0 = (size_t)sp * TPS * 32;
#pragma unroll
    for (int it = 0; it < 4; ++it) {
      pk[it] = *(const u16x8*)(Kb + (kg0 + krow + it * 8) * Cc + kch * 8);
      pv[it] = *(const u16x8*)(Vb + (size_t)(it * 64 + vc) * Nn + kg0 + vp * 8);
    }
  }

#pragma unroll 1
  for (int kb = 0; kb < TPS; ++kb) {
    __syncthreads();   // prev tile's LDS reads done
    // ---- regs -> LDS (swizzled on the LDS side) ----
#pragma unroll
    for (int it = 0; it < 4; ++it) {
      const int row = krow + it * 8;
      *(u16x8*)(sK + row * 256 + ((kch ^ (row & 7)) << 3)) = pk[it];
      const int c = it * 64 + vc;
      *(u16x8*)(sV + c * 32 + ((vp ^ ((c >> 1) & 3)) << 3)) = pv[it];
    }
    __syncthreads();
    // ---- prefetch next tile (drains at next tile's ds_write) ----
    if (kb + 1 < TPS) {
      const size_t kg0 = ((size_t)sp * TPS + kb + 1) * 32;
#pragma unroll
      for (int it = 0; it < 4; ++it) {
        pk[it] = *(const u16x8*)(Kb + (kg0 + krow + it * 8) * Cc + kch * 8);
        pv[it] = *(const u16x8*)(Vb + (size_t)(it * 64 + vc) * Nn + kg0 + vp * 8);
      }
    }

    // ---- S = Q K^T (two 16-key blocks) ----
    f32x4 s0 = {0.f, 0.f, 0.f, 0.f}, s1 = s0;
#pragma unroll
    for (int kc = 0; kc < 8; ++kc) {
      const int ch = ((kc * 4 + quad) ^ (l15 & 7)) << 3;
      const u16x8 k0 = *(const u16x8*)(sK + l15 * 256 + ch);
      const u16x8 k1 = *(const u16x8*)(sK + (16 + l15) * 256 + ch);
      s0 = mfma16(qf[kc], k0, s0);
      s1 = mfma16(qf[kc], k1, s1);
    }

    // ---- online softmax (4 independent DPP chains) ----
    float m0[4], al[4], sums[4];
#pragma unroll
    for (int r = 0; r < 4; ++r) m0[r] = fmaxf(s0[r], s1[r]);
#pragma unroll
    for (int r = 0; r < 4; ++r) m0[r] = rowmax16(m0[r]);
#pragma unroll
    for (int r = 0; r < 4; ++r) {
      const float mn = fmaxf(mrow[r], m0[r]);
      al[r] = exp2f((mrow[r] - mn) * L2E);
      mrow[r] = mn;
      const float p0 = exp2f((s0[r] - mn) * L2E);
      const float p1 = exp2f((s1[r] - mn) * L2E);
      s0[r] = p0; s1[r] = p1;
      sums[r] = p0 + p1;
    }
#pragma unroll
    for (int r = 0; r < 4; ++r) sums[r] = rowsum16(sums[r]);
#pragma unroll
    for (int r = 0; r < 4; ++r) lrow[r] = lrow[r] * al[r] + sums[r];

    if (__any((al[0] < 1.f) | (al[1] < 1.f) | (al[2] < 1.f) | (al[3] < 1.f))) {
#pragma unroll
      for (int i = 0; i < 16; ++i) {
#pragma unroll
        for (int r = 0; r < 4; ++r) o[i][r] *= al[r];
      }
    }

    // ---- P: C/D -> sP (wave-local) -> A layout ----
    {
      u16* P = sP + w * 512;
      const int kch0 = l15 >> 3;
#pragma unroll
      for (int r = 0; r < 4; ++r) {
        const int row = quad * 4 + r;
        const int gx = r ^ quad;
        P[row * 32 + ((kch0 ^ gx) << 3) + (l15 & 7)] = f2h(s0[r]);
        P[row * 32 + (((2 + kch0) ^ gx) << 3) + (l15 & 7)] = f2h(s1[r]);
      }
    }
    __builtin_amdgcn_s_waitcnt(0xC07F);  // lgkmcnt(0)
    const u16x8 pf = *(const u16x8*)(sP + w * 512 + l15 * 32 + ((quad ^ gl) << 3));

    // ---- O += P V (16 independent accumulators) ----
#pragma unroll
    for (int cb2 = 0; cb2 < 16; ++cb2) {
      const int c = cb2 * 16 + l15;
      const u16x8 vf = *(const u16x8*)(sV + c * 32 + ((quad ^ ((c >> 1) & 3)) << 3));
      o[cb2] = mfma16(pf, vf, o[cb2]);
    }
  }

  // ---- epilogue: unnormalized partials ----
  float* Ob = Opart + ((size_t)sp * Bb + b) * (size_t)Cc * Nn;
#pragma unroll
  for (int cb2 = 0; cb2 < 16; ++cb2) {
    const int c = cb2 * 16 + l15;
    *(f32x4*)(Ob + (size_t)c * Nn + q0 + w * 16 + quad * 4) = o[cb2];
  }
  if (l15 == 0) {
    float* mlb = Ml + ((size_t)sp * Bb + b) * (size_t)Nn * 2;
#pragma unroll
    for (int r = 0; r < 4; ++r) {
      const int n = q0 + w * 16 + quad * 4 + r;
      mlb[n * 2]     = mrow[r];
      mlb[n * 2 + 1] = lrow[r];
    }
  }
}

// ---------------------------------------------------------------------------
// Merge the KSPLIT K-split partials.
// ---------------------------------------------------------------------------
__global__ void merge_kernel(const float* __restrict__ Opart,
                             const float* __restrict__ Ml,
                             float* __restrict__ out)
{
  const int idx = blockIdx.x * 256 + threadIdx.x;
  const int n4 = idx % 576;
  const int bc = idx / 576;
  const int b  = bc >> 8;
  const size_t o0off = (size_t)bc * Nn + n4 * 4;
  const size_t ostride = (size_t)Bb * Cc * Nn;

  f32x4 ov[KSPLIT];
  float mv[KSPLIT][4], lv[KSPLIT][4];
#pragma unroll
  for (int s = 0; s < KSPLIT; ++s) {
    ov[s] = *(const f32x4*)(Opart + o0off + (size_t)s * ostride);
    const float* ml = Ml + ((size_t)s * Bb + b) * (size_t)Nn * 2 + n4 * 8;
    const f32x4 u0 = *(const f32x4*)ml;
    const f32x4 u1 = *(const f32x4*)(ml + 4);
#pragma unroll
    for (int j = 0; j < 4; ++j) {
      mv[s][j] = (j < 2) ? u0[j * 2]     : u1[(j - 2) * 2];
      lv[s][j] = (j < 2) ? u0[j * 2 + 1] : u1[(j - 2) * 2 + 1];
    }
  }

  f32x4 r;
#pragma unroll
  for (int j = 0; j < 4; ++j) {
    float m = mv[0][j];
#pragma unroll
    for (int s = 1; s < KSPLIT; ++s) m = fmaxf(m, mv[s][j]);
    float num = 0.f, den = 0.f;
#pragma unroll
    for (int s = 0; s < KSPLIT; ++s) {
      const float ws = exp2f((mv[s][j] - m) * L2E);
      num += ov[s][j] * ws;
      den += lv[s][j] * ws;
    }
    r[j] = num / den;
  }
  *(f32x4*)(out + o0off) = r;
}

extern "C" void kernel_launch(void* const* d_in, const int* in_sizes, int n_in,
                              void* d_out, int out_size, void* d_ws, size_t ws_size,
                              hipStream_t stream) {
  const float* x  = (const float*)d_in[0];
  const float* y  = (const float*)d_in[1];
  const float* Wq = (const float*)d_in[2];
  const float* bq = (const float*)d_in[3];
  const float* Wk = (const float*)d_in[4];
  const float* bk = (const float*)d_in[5];
  const float* Wv = (const float*)d_in[6];
  const float* bv = (const float*)d_in[7];
  float* out = (float*)d_out;

  const size_t NC = (size_t)Bb * Nn * Cc;   // 4,718,592
  u16* Qf = (u16*)d_ws;
  u16* Kf = Qf + NC;
  u16* Vf = Kf + NC;
  u16* Wf = Vf + NC;
  float* Opart = (float*)(Wf + 3 * 65536);
  float* Ml    = Opart + (size_t)KSPLIT * NC;

  hipLaunchKernelGGL(prep_kernel, dim3(96), dim3(256), 0, stream,
                     Wq, Wk, Wv, Wf);
  hipLaunchKernelGGL(proj_kernel, dim3(Bb, PQT, 3), dim3(256), 0, stream,
                     x, y, Wf, bq, bk, bv, Qf, Kf, Vf);
  hipLaunchKernelGGL(attn_kernel, dim3(Bb, QTILES, KSPLIT), dim3(256), 0, stream,
                     Qf, Kf, Vf, Opart, Ml);
  hipLaunchKernelGGL(merge_kernel, dim3(4608), dim3(256), 0, stream,
                     Opart, Ml, out);
}

// Round 2
// 332.038 us; speedup vs baseline: 1.5054x; 1.5054x over previous
//
#include <hip/hip_runtime.h>
#include <stdint.h>

#define Bb 8
#define Cc 256
#define Nn 2304
#define PQT 36   // proj: 64-token tiles
#define QTILES 36
#define KSPLIT 3
#define TPS 24   // 32-key tiles per split (72 total / KSPLIT)
#define L2E 1.44269504088896f

#define AS1 __attribute__((address_space(1)))
#define AS3 __attribute__((address_space(3)))

typedef unsigned short u16;
typedef _Float16 h16;
typedef h16  h16x8 __attribute__((ext_vector_type(8)));
typedef u16  u16x8 __attribute__((ext_vector_type(8)));
typedef float f32x4 __attribute__((ext_vector_type(4)));

static __device__ __forceinline__ u16 f2h(float f) {
  return __builtin_bit_cast(u16, (h16)f);
}
static __device__ __forceinline__ h16x8 ash(u16x8 v) {
  return __builtin_bit_cast(h16x8, v);
}
static __device__ __forceinline__ f32x4 mfma16(u16x8 a, u16x8 b, f32x4 c) {
  return __builtin_amdgcn_mfma_f32_16x16x32_f16(ash(a), ash(b), c, 0, 0, 0);
}

// DPP row_ror reductions over 16 lanes (VALU pipe)
template <int CTRL>
static __device__ __forceinline__ float dppmov(float x) {
  return __builtin_bit_cast(float,
      __builtin_amdgcn_mov_dpp(__builtin_bit_cast(int, x), CTRL, 0xF, 0xF, true));
}
static __device__ __forceinline__ float rowmax16(float x) {
  x = fmaxf(x, dppmov<0x121>(x));
  x = fmaxf(x, dppmov<0x122>(x));
  x = fmaxf(x, dppmov<0x124>(x));
  x = fmaxf(x, dppmov<0x128>(x));
  return x;
}
static __device__ __forceinline__ float rowsum16(float x) {
  x += dppmov<0x121>(x);
  x += dppmov<0x122>(x);
  x += dppmov<0x124>(x);
  x += dppmov<0x128>(x);
  return x;
}

// ---------------------------------------------------------------------------
// Prep: Wq,Wk,Wv fp32 [C][C] -> fp16 Wf [3][C*C].
// ---------------------------------------------------------------------------
__global__ void prep_kernel(const float* __restrict__ Wq,
                            const float* __restrict__ Wk,
                            const float* __restrict__ Wv,
                            u16* __restrict__ Wf)
{
  const int tid = blockIdx.x * 256 + threadIdx.x;
  const int m   = tid >> 13;
  const int off = (tid & 8191) * 8;
  const float* src = (m == 0) ? Wq : (m == 1) ? Wk : Wv;
  const f32x4 a = *(const f32x4*)(src + off);
  const f32x4 c = *(const f32x4*)(src + off + 4);
  u16x8 o;
#pragma unroll
  for (int j = 0; j < 4; ++j) { o[j] = f2h(a[j]); o[j + 4] = f2h(c[j]); }
  *(u16x8*)(Wf + (size_t)m * 65536 + off) = o;
}

// ---------------------------------------------------------------------------
// Projection (all fp16, 1-term). W staged 32 full rows at a time in LDS
// (coalesced 512B row loads, XOR-swizzled b128 reads). z=0: Q [B][N][C],
// z=1: K [B][N][C], z=2: V^T [B][C][N]. grid (8,36,3), block 256.
// ---------------------------------------------------------------------------
__global__ __launch_bounds__(256, 4) void proj_kernel(
    const float* __restrict__ x, const float* __restrict__ y,
    const u16* __restrict__ Wf,
    const float* __restrict__ bq, const float* __restrict__ bk,
    const float* __restrict__ bv,
    u16* __restrict__ Qf, u16* __restrict__ Kf, u16* __restrict__ Vf)
{
  __shared__ u16 sW[32 * 256];   // 16 KB
  const int t    = threadIdx.x;
  const int b    = blockIdx.x;
  const int q0   = blockIdx.y * 64;
  const int z    = blockIdx.z;
  const int lane = t & 63;
  const int w    = t >> 6;
  const int quad = lane >> 4;
  const int l15  = lane & 15;

  const u16* WZ = Wf + (size_t)z * 65536;

  // token fragments (A for z<2, B for z==2): lane l15 -> token, k=quad*8+j
  const float* src = (z == 0) ? x : y;
  const int tok = q0 + w * 16 + l15;
  u16x8 af[8];
#pragma unroll
  for (int kc = 0; kc < 8; ++kc) {
    const float* p = src + ((size_t)b * Cc + kc * 32 + quad * 8) * Nn + tok;
    float v[8];
#pragma unroll
    for (int j = 0; j < 8; ++j) v[j] = p[(size_t)j * Nn];
#pragma unroll
    for (int j = 0; j < 8; ++j) af[kc][j] = f2h(v[j]);
  }

  f32x4 acc[16];
#pragma unroll
  for (int i = 0; i < 16; ++i) acc[i] = (f32x4){0.f, 0.f, 0.f, 0.f};

#pragma unroll 1
  for (int rg = 0; rg < 8; ++rg) {   // 32 c_out rows per round
    __syncthreads();
#pragma unroll
    for (int it = 0; it < 4; ++it) {
      const int id = it * 256 + t;
      const int row = id >> 5, gch = id & 31;
      const u16x8 v = *(const u16x8*)(WZ + (size_t)(rg * 32 + row) * 256 + gch * 8);
      *(u16x8*)(sW + row * 256 + ((gch ^ (row & 7)) << 3)) = v;
    }
    __syncthreads();
    if (z < 2) {
#pragma unroll
      for (int cbl = 0; cbl < 2; ++cbl) {
        const int rl = cbl * 16 + l15;
        f32x4 a = acc[rg * 2 + cbl];
#pragma unroll
        for (int kc = 0; kc < 8; ++kc) {
          const u16x8 bf = *(const u16x8*)(sW + rl * 256 + (((kc * 4 + quad) ^ (rl & 7)) << 3));
          a = mfma16(af[kc], bf, a);
        }
        acc[rg * 2 + cbl] = a;
      }
    } else {
#pragma unroll
      for (int mt = 0; mt < 2; ++mt) {
        const int rl = mt * 16 + l15;
        f32x4 a = acc[rg * 2 + mt];
#pragma unroll
        for (int kc = 0; kc < 8; ++kc) {
          const u16x8 wfr = *(const u16x8*)(sW + rl * 256 + (((kc * 4 + quad) ^ (rl & 7)) << 3));
          a = mfma16(wfr, af[kc], a);
        }
        acc[rg * 2 + mt] = a;
      }
    }
  }

  // epilogues
  if (z < 2) {
    const float* bias = (z == 0) ? bq : bk;
    u16* O = (z == 0) ? Qf : Kf;
#pragma unroll
    for (int cb = 0; cb < 16; ++cb) {
      const int co = cb * 16 + l15;
      const float bs = bias[co];
      const size_t base = ((size_t)b * Nn + q0 + w * 16 + quad * 4) * Cc + co;
#pragma unroll
      for (int r = 0; r < 4; ++r)
        O[base + (size_t)r * Cc] = f2h(acc[cb][r] + bs);
    }
  } else {
#pragma unroll
    for (int cb = 0; cb < 16; ++cb) {
      const int crow = cb * 16 + quad * 4;
#pragma unroll
      for (int r = 0; r < 4; ++r)
        Vf[((size_t)b * Cc + crow + r) * Nn + q0 + w * 16 + l15] =
            f2h(acc[cb][r] + bv[crow + r]);
    }
  }
}

// ---------------------------------------------------------------------------
// Flash attention v8: fp16, 32-key tiles. K/V staged via global_load_lds DMA
// with PRE-SWIZZLED per-lane source addresses (linear LDS dest + swizzled
// read = same involution as before; LDS contents bit-identical to v7).
// Frees the 32 prefetch VGPRs -> honest unified reg count ~115 < 128 ->
// 4 blocks/CU without spills. grid (8,36,3) = 864 blocks, all resident
// (3.375/CU), occupancy ~42%. LDS 36 KB single-buffered; DMA for tile kb+1
// issued after the end-of-tile barrier, drained at the top-of-tile barrier.
// ---------------------------------------------------------------------------
__global__ __launch_bounds__(256, 4) void attn_kernel(
    const u16* __restrict__ Qf, const u16* __restrict__ Kf,
    const u16* __restrict__ Vf, float* __restrict__ Opart,
    float* __restrict__ Ml)
{
  __shared__ u16 sK[32 * 256];   // 16 KB
  __shared__ u16 sV[256 * 32];   // 16 KB
  __shared__ u16 sP[4 * 512];    //  4 KB
  const int t    = threadIdx.x;
  const int b    = blockIdx.x;
  const int q0   = blockIdx.y * 64;
  const int sp   = blockIdx.z;
  const int lane = t & 63;
  const int w    = t >> 6;
  const int quad = lane >> 4;
  const int l15  = lane & 15;

  // Q A-frags
  u16x8 qf[8];
  {
    const size_t qrow = ((size_t)b * Nn + q0 + w * 16 + l15) * Cc;
#pragma unroll
    for (int kc = 0; kc < 8; ++kc)
      qf[kc] = *(const u16x8*)(Qf + qrow + kc * 32 + quad * 8);
  }

  f32x4 o[16];
#pragma unroll
  for (int i = 0; i < 16; ++i) o[i] = (f32x4){0.f, 0.f, 0.f, 0.f};
  float mrow[4] = {-3e38f, -3e38f, -3e38f, -3e38f};
  float lrow[4] = {0.f, 0.f, 0.f, 0.f};

  const u16* Kb = Kf + (size_t)b * Nn * Cc;
  const u16* Vb = Vf + (size_t)b * Cc * Nn;
  const int gl = (l15 & 3) ^ ((l15 >> 2) & 3);

  // --- DMA staging geometry: instr i = w + 4*it covers 1KB of LDS.
  // K: LDS u16 off = i*512 + lane*8 = row*256 + ch*8, row = 2w+(lane>>5)+8it.
  //    row&7 = 2w+(lane>>5) (it-independent). Source chunk = ch ^ (row&7).
  // V: LDS u16 off = c*32 + p*8, c = w*16+(lane>>2)+64it, p = lane&3.
  //    (c>>1)&3 it-independent. Source chunk = p ^ ((c>>1)&3).
  const int rbase = 2 * w + (lane >> 5);                 // 0..7 == row&7
  const int kcol  = ((lane & 31) ^ rbase) << 3;
  const int cV    = w * 16 + (lane >> 2);                // 0..63
  const int vcol  = ((lane & 3) ^ ((cV >> 1) & 3)) << 3;
  const u16* kp0 = Kb + ((size_t)(sp * TPS * 32 + rbase)) * Cc + kcol;
  const u16* vp0 = Vb + (size_t)cV * Nn + sp * TPS * 32 + vcol;

  auto stage = [&](int kb) {
    const u16* kp = kp0 + (size_t)kb * 32 * Cc;
    const u16* vp = vp0 + kb * 32;
#pragma unroll
    for (int it = 0; it < 4; ++it) {
      __builtin_amdgcn_global_load_lds(
          (const AS1 void*)(kp + (size_t)it * 8 * Cc),
          (AS3 void*)&sK[(w + 4 * it) * 512], 16, 0, 0);
      __builtin_amdgcn_global_load_lds(
          (const AS1 void*)(vp + (size_t)it * 64 * Nn),
          (AS3 void*)&sV[(w + 4 * it) * 512], 16, 0, 0);
    }
  };

  stage(0);

#pragma unroll 1
  for (int kb = 0; kb < TPS; ++kb) {
    __builtin_amdgcn_s_waitcnt(0x0F70);  // vmcnt(0): own DMA drained
    __syncthreads();                     // all waves' DMA visible

    // ---- S = Q K^T (two 16-key blocks) ----
    f32x4 s0 = {0.f, 0.f, 0.f, 0.f}, s1 = s0;
#pragma unroll
    for (int kc = 0; kc < 8; ++kc) {
      const int ch = ((kc * 4 + quad) ^ (l15 & 7)) << 3;
      const u16x8 k0 = *(const u16x8*)(sK + l15 * 256 + ch);
      const u16x8 k1 = *(const u16x8*)(sK + (16 + l15) * 256 + ch);
      s0 = mfma16(qf[kc], k0, s0);
      s1 = mfma16(qf[kc], k1, s1);
    }

    // ---- online softmax (4 independent DPP chains) ----
    float m0[4], al[4], sums[4];
#pragma unroll
    for (int r = 0; r < 4; ++r) m0[r] = fmaxf(s0[r], s1[r]);
#pragma unroll
    for (int r = 0; r < 4; ++r) m0[r] = rowmax16(m0[r]);
#pragma unroll
    for (int r = 0; r < 4; ++r) {
      const float mn = fmaxf(mrow[r], m0[r]);
      al[r] = exp2f((mrow[r] - mn) * L2E);
      mrow[r] = mn;
      const float p0 = exp2f((s0[r] - mn) * L2E);
      const float p1 = exp2f((s1[r] - mn) * L2E);
      s0[r] = p0; s1[r] = p1;
      sums[r] = p0 + p1;
    }
#pragma unroll
    for (int r = 0; r < 4; ++r) sums[r] = rowsum16(sums[r]);
#pragma unroll
    for (int r = 0; r < 4; ++r) lrow[r] = lrow[r] * al[r] + sums[r];

    if (__any((al[0] < 1.f) | (al[1] < 1.f) | (al[2] < 1.f) | (al[3] < 1.f))) {
#pragma unroll
      for (int i = 0; i < 16; ++i) {
#pragma unroll
        for (int r = 0; r < 4; ++r) o[i][r] *= al[r];
      }
    }

    // ---- P: C/D -> sP (wave-local) -> A layout ----
    {
      u16* P = sP + w * 512;
      const int kch0 = l15 >> 3;
#pragma unroll
      for (int r = 0; r < 4; ++r) {
        const int row = quad * 4 + r;
        const int gx = r ^ quad;
        P[row * 32 + ((kch0 ^ gx) << 3) + (l15 & 7)] = f2h(s0[r]);
        P[row * 32 + (((2 + kch0) ^ gx) << 3) + (l15 & 7)] = f2h(s1[r]);
      }
    }
    __builtin_amdgcn_s_waitcnt(0xC07F);  // lgkmcnt(0)
    const u16x8 pf = *(const u16x8*)(sP + w * 512 + l15 * 32 + ((quad ^ gl) << 3));

    // ---- O += P V (16 independent accumulators) ----
#pragma unroll
    for (int cb2 = 0; cb2 < 16; ++cb2) {
      const int c = cb2 * 16 + l15;
      const u16x8 vf = *(const u16x8*)(sV + c * 32 + ((quad ^ ((c >> 1) & 3)) << 3));
      o[cb2] = mfma16(pf, vf, o[cb2]);
    }

    __syncthreads();                     // all waves done reading sK/sV
    if (kb + 1 < TPS) stage(kb + 1);     // async DMA for next tile
  }

  // ---- epilogue: unnormalized partials ----
  float* Ob = Opart + ((size_t)sp * Bb + b) * (size_t)Cc * Nn;
#pragma unroll
  for (int cb2 = 0; cb2 < 16; ++cb2) {
    const int c = cb2 * 16 + l15;
    *(f32x4*)(Ob + (size_t)c * Nn + q0 + w * 16 + quad * 4) = o[cb2];
  }
  if (l15 == 0) {
    float* mlb = Ml + ((size_t)sp * Bb + b) * (size_t)Nn * 2;
#pragma unroll
    for (int r = 0; r < 4; ++r) {
      const int n = q0 + w * 16 + quad * 4 + r;
      mlb[n * 2]     = mrow[r];
      mlb[n * 2 + 1] = lrow[r];
    }
  }
}

// ---------------------------------------------------------------------------
// Merge the KSPLIT K-split partials.
// ---------------------------------------------------------------------------
__global__ void merge_kernel(const float* __restrict__ Opart,
                             const float* __restrict__ Ml,
                             float* __restrict__ out)
{
  const int idx = blockIdx.x * 256 + threadIdx.x;
  const int n4 = idx % 576;
  const int bc = idx / 576;
  const int b  = bc >> 8;
  const size_t o0off = (size_t)bc * Nn + n4 * 4;
  const size_t ostride = (size_t)Bb * Cc * Nn;

  f32x4 ov[KSPLIT];
  float mv[KSPLIT][4], lv[KSPLIT][4];
#pragma unroll
  for (int s = 0; s < KSPLIT; ++s) {
    ov[s] = *(const f32x4*)(Opart + o0off + (size_t)s * ostride);
    const float* ml = Ml + ((size_t)s * Bb + b) * (size_t)Nn * 2 + n4 * 8;
    const f32x4 u0 = *(const f32x4*)ml;
    const f32x4 u1 = *(const f32x4*)(ml + 4);
#pragma unroll
    for (int j = 0; j < 4; ++j) {
      mv[s][j] = (j < 2) ? u0[j * 2]     : u1[(j - 2) * 2];
      lv[s][j] = (j < 2) ? u0[j * 2 + 1] : u1[(j - 2) * 2 + 1];
    }
  }

  f32x4 r;
#pragma unroll
  for (int j = 0; j < 4; ++j) {
    float m = mv[0][j];
#pragma unroll
    for (int s = 1; s < KSPLIT; ++s) m = fmaxf(m, mv[s][j]);
    float num = 0.f, den = 0.f;
#pragma unroll
    for (int s = 0; s < KSPLIT; ++s) {
      const float ws = exp2f((mv[s][j] - m) * L2E);
      num += ov[s][j] * ws;
      den += lv[s][j] * ws;
    }
    r[j] = num / den;
  }
  *(f32x4*)(out + o0off) = r;
}

extern "C" void kernel_launch(void* const* d_in, const int* in_sizes, int n_in,
                              void* d_out, int out_size, void* d_ws, size_t ws_size,
                              hipStream_t stream) {
  const float* x  = (const float*)d_in[0];
  const float* y  = (const float*)d_in[1];
  const float* Wq = (const float*)d_in[2];
  const float* bq = (const float*)d_in[3];
  const float* Wk = (const float*)d_in[4];
  const float* bk = (const float*)d_in[5];
  const float* Wv = (const float*)d_in[6];
  const float* bv = (const float*)d_in[7];
  float* out = (float*)d_out;

  const size_t NC = (size_t)Bb * Nn * Cc;   // 4,718,592
  u16* Qf = (u16*)d_ws;
  u16* Kf = Qf + NC;
  u16* Vf = Kf + NC;
  u16* Wf = Vf + NC;
  float* Opart = (float*)(Wf + 3 * 65536);
  float* Ml    = Opart + (size_t)KSPLIT * NC;

  hipLaunchKernelGGL(prep_kernel, dim3(96), dim3(256), 0, stream,
                     Wq, Wk, Wv, Wf);
  hipLaunchKernelGGL(proj_kernel, dim3(Bb, PQT, 3), dim3(256), 0, stream,
                     x, y, Wf, bq, bk, bv, Qf, Kf, Vf);
  hipLaunchKernelGGL(attn_kernel, dim3(Bb, QTILES, KSPLIT), dim3(256), 0, stream,
                     Qf, Kf, Vf, Opart, Ml);
  hipLaunchKernelGGL(merge_kernel, dim3(4608), dim3(256), 0, stream,
                     Opart, Ml, out);
}

// Round 3
// 237.449 us; speedup vs baseline: 2.1050x; 1.3984x over previous
//
#include <hip/hip_runtime.h>
#include <stdint.h>

#define Bb 8
#define Cc 256
#define Nn 2304
#define PQT 36   // proj: 64-token tiles
#define QTILES 36
#define KSPLIT 2
#define TPS 36   // 32-key tiles per split (72 total / KSPLIT)
#define L2E 1.44269504088896f
#define DEFER_THR 8.0f

#define AS1 __attribute__((address_space(1)))
#define AS3 __attribute__((address_space(3)))

typedef unsigned short u16;
typedef unsigned int u32;
typedef _Float16 h16;
typedef h16  h16x8 __attribute__((ext_vector_type(8)));
typedef h16  h16x2 __attribute__((ext_vector_type(2)));
typedef u16  u16x8 __attribute__((ext_vector_type(8)));
typedef u32  u32x4 __attribute__((ext_vector_type(4)));
typedef float f32x4 __attribute__((ext_vector_type(4)));
typedef float f32x2 __attribute__((ext_vector_type(2)));

static __device__ __forceinline__ u16 f2h(float f) {
  return __builtin_bit_cast(u16, (h16)f);
}
static __device__ __forceinline__ h16x8 ash(u16x8 v) {
  return __builtin_bit_cast(h16x8, v);
}
static __device__ __forceinline__ f32x4 mfma16(u16x8 a, u16x8 b, f32x4 c) {
  return __builtin_amdgcn_mfma_f32_16x16x32_f16(ash(a), ash(b), c, 0, 0, 0);
}
// pack 2 f32 -> 2 f16 (RTZ), as one u32
static __device__ __forceinline__ u32 pkf16(float a, float b) {
  return __builtin_bit_cast(u32, __builtin_amdgcn_cvt_pkrtz(a, b));
}

// ---------------------------------------------------------------------------
// Prep: Wq,Wk,Wv fp32 [C][C] -> fp16 Wf [3][C*C].
// ---------------------------------------------------------------------------
__global__ void prep_kernel(const float* __restrict__ Wq,
                            const float* __restrict__ Wk,
                            const float* __restrict__ Wv,
                            u16* __restrict__ Wf)
{
  const int tid = blockIdx.x * 256 + threadIdx.x;
  const int m   = tid >> 13;
  const int off = (tid & 8191) * 8;
  const float* src = (m == 0) ? Wq : (m == 1) ? Wk : Wv;
  const f32x4 a = *(const f32x4*)(src + off);
  const f32x4 c = *(const f32x4*)(src + off + 4);
  u16x8 o;
#pragma unroll
  for (int j = 0; j < 4; ++j) { o[j] = f2h(a[j]); o[j + 4] = f2h(c[j]); }
  *(u16x8*)(Wf + (size_t)m * 65536 + off) = o;
}

// ---------------------------------------------------------------------------
// Projection (all fp16, 1-term). W staged 32 full rows at a time in LDS
// (coalesced 512B row loads, XOR-swizzled b128 reads). z=0: Q [B][N][C],
// z=1: K [B][N][C], z=2: V^T [B][C][N]. grid (8,36,3), block 256.
// ---------------------------------------------------------------------------
__global__ __launch_bounds__(256, 4) void proj_kernel(
    const float* __restrict__ x, const float* __restrict__ y,
    const u16* __restrict__ Wf,
    const float* __restrict__ bq, const float* __restrict__ bk,
    const float* __restrict__ bv,
    u16* __restrict__ Qf, u16* __restrict__ Kf, u16* __restrict__ Vf)
{
  __shared__ u16 sW[32 * 256];   // 16 KB
  const int t    = threadIdx.x;
  const int b    = blockIdx.x;
  const int q0   = blockIdx.y * 64;
  const int z    = blockIdx.z;
  const int lane = t & 63;
  const int w    = t >> 6;
  const int quad = lane >> 4;
  const int l15  = lane & 15;

  const u16* WZ = Wf + (size_t)z * 65536;

  // token fragments (A for z<2, B for z==2): lane l15 -> token, k=quad*8+j
  const float* src = (z == 0) ? x : y;
  const int tok = q0 + w * 16 + l15;
  u16x8 af[8];
#pragma unroll
  for (int kc = 0; kc < 8; ++kc) {
    const float* p = src + ((size_t)b * Cc + kc * 32 + quad * 8) * Nn + tok;
    float v[8];
#pragma unroll
    for (int j = 0; j < 8; ++j) v[j] = p[(size_t)j * Nn];
#pragma unroll
    for (int j = 0; j < 8; ++j) af[kc][j] = f2h(v[j]);
  }

  f32x4 acc[16];
#pragma unroll
  for (int i = 0; i < 16; ++i) acc[i] = (f32x4){0.f, 0.f, 0.f, 0.f};

#pragma unroll 1
  for (int rg = 0; rg < 8; ++rg) {   // 32 c_out rows per round
    __syncthreads();
#pragma unroll
    for (int it = 0; it < 4; ++it) {
      const int id = it * 256 + t;
      const int row = id >> 5, gch = id & 31;
      const u16x8 v = *(const u16x8*)(WZ + (size_t)(rg * 32 + row) * 256 + gch * 8);
      *(u16x8*)(sW + row * 256 + ((gch ^ (row & 7)) << 3)) = v;
    }
    __syncthreads();
    if (z < 2) {
#pragma unroll
      for (int cbl = 0; cbl < 2; ++cbl) {
        const int rl = cbl * 16 + l15;
        f32x4 a = acc[rg * 2 + cbl];
#pragma unroll
        for (int kc = 0; kc < 8; ++kc) {
          const u16x8 bf = *(const u16x8*)(sW + rl * 256 + (((kc * 4 + quad) ^ (rl & 7)) << 3));
          a = mfma16(af[kc], bf, a);
        }
        acc[rg * 2 + cbl] = a;
      }
    } else {
#pragma unroll
      for (int mt = 0; mt < 2; ++mt) {
        const int rl = mt * 16 + l15;
        f32x4 a = acc[rg * 2 + mt];
#pragma unroll
        for (int kc = 0; kc < 8; ++kc) {
          const u16x8 wfr = *(const u16x8*)(sW + rl * 256 + (((kc * 4 + quad) ^ (rl & 7)) << 3));
          a = mfma16(wfr, af[kc], a);
        }
        acc[rg * 2 + mt] = a;
      }
    }
  }

  // epilogues
  if (z < 2) {
    const float* bias = (z == 0) ? bq : bk;
    u16* O = (z == 0) ? Qf : Kf;
#pragma unroll
    for (int cb = 0; cb < 16; ++cb) {
      const int co = cb * 16 + l15;
      const float bs = bias[co];
      const size_t base = ((size_t)b * Nn + q0 + w * 16 + quad * 4) * Cc + co;
#pragma unroll
      for (int r = 0; r < 4; ++r)
        O[base + (size_t)r * Cc] = f2h(acc[cb][r] + bs);
    }
  } else {
#pragma unroll
    for (int cb = 0; cb < 16; ++cb) {
      const int crow = cb * 16 + quad * 4;
#pragma unroll
      for (int r = 0; r < 4; ++r)
        Vf[((size_t)b * Cc + crow + r) * Nn + q0 + w * 16 + l15] =
            f2h(acc[cb][r] + bv[crow + r]);
    }
  }
}

// ---------------------------------------------------------------------------
// Flash attention v9: swapped-operand QK (S^T = mfma(K,Q): col=lane=query) so
// softmax is lane-local (7 fmax + 2 shfl_xor; no DPP chains, no sP LDS
// round-trip). Key-relabeling permutation kappa(i)=((i>>2)&3)*8+(i&3)+
// ((i>>4)<<2) is folded into the K-DMA source row, which makes each lane's 8
// P-values land exactly on its own B-operand key slots (k=quad*8+j) for the
// swapped PV mfma(V^T, P) -> D[c][q]. Zero cross-lane ops for P.
// Defer-max (THR=8): o-rescale only when the running max grows >8.
// K/V LDS layouts + DMA staging byte-identical to v8. KSPLIT=2 (occupancy
// proven non-binding in r1/r2), launch_bounds(256,3): 576 blocks resident,
// ~140 VGPR < 170 cap (r1 lesson: never starve the allocator into spilling).
// ---------------------------------------------------------------------------
__global__ __launch_bounds__(256, 3) void attn_kernel(
    const u16* __restrict__ Qf, const u16* __restrict__ Kf,
    const u16* __restrict__ Vf, float* __restrict__ Opart,
    float* __restrict__ Ml)
{
  __shared__ u16 sK[32 * 256];   // 16 KB
  __shared__ u16 sV[256 * 32];   // 16 KB
  const int t    = threadIdx.x;
  const int b    = blockIdx.x;
  const int q0   = blockIdx.y * 64;
  const int sp   = blockIdx.z;
  const int lane = t & 63;
  const int w    = t >> 6;
  const int quad = lane >> 4;
  const int l15  = lane & 15;

  // Q fragments: lane l15 -> query token, elems c = kc*32 + quad*8 + j.
  // Used as B-operand now (col = lane = query); same registers as before.
  u16x8 qf[8];
  {
    const size_t qrow = ((size_t)b * Nn + q0 + w * 16 + l15) * Cc;
#pragma unroll
    for (int kc = 0; kc < 8; ++kc)
      qf[kc] = *(const u16x8*)(Qf + qrow + kc * 32 + quad * 8);
  }

  f32x4 o[16];   // O^T accum: D[c][q], c = cb*16 + quad*4 + r, q = l15
#pragma unroll
  for (int i = 0; i < 16; ++i) o[i] = (f32x4){0.f, 0.f, 0.f, 0.f};
  float mrow = -3e38f;   // per-lane scalar: one query per lane
  float lrow = 0.f;

  const u16* Kb = Kf + (size_t)b * Nn * Cc;
  const u16* Vb = Vf + (size_t)b * Cc * Nn;

  // --- DMA staging geometry (per-thread constants), identical LDS image to
  // v8 EXCEPT the K source ROW is permuted by kappa (see header comment).
  // K: dest row = rbase + 8*it, rbase = 2w + (lane>>5); row&7 = rbase.
  const int rbase = 2 * w + (lane >> 5);
  const int kcol  = ((lane & 31) ^ rbase) << 3;          // swizzled source col
  const int rb2 = rbase >> 2, rb3 = rbase & 3;
  int koff[4];   // u16 offsets of the permuted source row + col, per it
#pragma unroll
  for (int it = 0; it < 4; ++it) {
    const int key = (((rb2 + 2 * it) & 3) << 3) + rb3 + ((it >> 1) << 2);
    koff[it] = key * Cc + kcol;
  }
  const u16* Kt = Kb + (size_t)(sp * TPS * 32) * Cc;
  // V: unchanged (identity column order).
  const int cV   = w * 16 + (lane >> 2);                 // 0..63
  const int vcol = ((lane & 3) ^ ((cV >> 1) & 3)) << 3;
  const u16* vp0 = Vb + (size_t)cV * Nn + sp * TPS * 32 + vcol;

  auto stage = [&](int kb) {
#pragma unroll
    for (int it = 0; it < 4; ++it) {
      __builtin_amdgcn_global_load_lds(
          (const AS1 void*)(Kt + (size_t)kb * 32 * Cc + koff[it]),
          (AS3 void*)&sK[(w + 4 * it) * 512], 16, 0, 0);
      __builtin_amdgcn_global_load_lds(
          (const AS1 void*)(vp0 + kb * 32 + (size_t)it * 64 * Nn),
          (AS3 void*)&sV[(w + 4 * it) * 512], 16, 0, 0);
    }
  };

  stage(0);

#pragma unroll 1
  for (int kb = 0; kb < TPS; ++kb) {
    __builtin_amdgcn_s_waitcnt(0x0F70);  // vmcnt(0): own DMA drained
    __syncthreads();                     // all waves' DMA visible

    // ---- S^T = K Q^T: D rows = staged keys (permuted labels), col = query.
    // Lane (l15, quad) ends with s0[r] = P-row 4quad+r, s1[r] = 16+4quad+r,
    // i.e. actual keys 8quad+r and 8quad+4+r: exactly its PV B slots.
    f32x4 s0 = {0.f, 0.f, 0.f, 0.f}, s1 = s0;
#pragma unroll
    for (int kc = 0; kc < 8; ++kc) {
      const int ch = ((kc * 4 + quad) ^ (l15 & 7)) << 3;
      const u16x8 k0 = *(const u16x8*)(sK + l15 * 256 + ch);
      const u16x8 k1 = *(const u16x8*)(sK + (16 + l15) * 256 + ch);
      s0 = mfma16(k0, qf[kc], s0);
      s1 = mfma16(k1, qf[kc], s1);
    }

    // ---- lane-local online softmax (query = l15; keys split across quads)
    float mloc = fmaxf(fmaxf(fmaxf(s0[0], s0[1]), fmaxf(s0[2], s0[3])),
                       fmaxf(fmaxf(s1[0], s1[1]), fmaxf(s1[2], s1[3])));
    mloc = fmaxf(mloc, __shfl_xor(mloc, 16, 64));
    mloc = fmaxf(mloc, __shfl_xor(mloc, 32, 64));
    const bool need = mloc > mrow + DEFER_THR;
    const float mn  = need ? mloc : mrow;
    const float al  = need ? exp2f((mrow - mn) * L2E) : 1.f;
    mrow = mn;

    float p0[4], p1[4];
    float sum = 0.f;
#pragma unroll
    for (int r = 0; r < 4; ++r) {
      p0[r] = exp2f((s0[r] - mn) * L2E);
      p1[r] = exp2f((s1[r] - mn) * L2E);
      sum += p0[r] + p1[r];
    }
    sum += __shfl_xor(sum, 16, 64);
    sum += __shfl_xor(sum, 32, 64);
    lrow = lrow * al + sum;

    if (__any(need)) {
#pragma unroll
      for (int i = 0; i < 16; ++i) {
#pragma unroll
        for (int r = 0; r < 4; ++r) o[i][r] *= al;
      }
    }

    // ---- P -> fp16 B-fragment, entirely in-lane (keys 8quad..8quad+7)
    u32x4 pw;
    pw[0] = pkf16(p0[0], p0[1]);
    pw[1] = pkf16(p0[2], p0[3]);
    pw[2] = pkf16(p1[0], p1[1]);
    pw[3] = pkf16(p1[2], p1[3]);
    const u16x8 pf = __builtin_bit_cast(u16x8, pw);

    // ---- O^T += V^T P (16 independent accumulators)
#pragma unroll
    for (int cb = 0; cb < 16; ++cb) {
      const int c = cb * 16 + l15;
      const u16x8 vf = *(const u16x8*)(sV + c * 32 + ((quad ^ ((c >> 1) & 3)) << 3));
      o[cb] = mfma16(vf, pf, o[cb]);
    }

    __syncthreads();                     // all waves done reading sK/sV
    if (kb + 1 < TPS) stage(kb + 1);     // async DMA for next tile
  }

  // ---- epilogue: unnormalized partials. o[cb][r]: c = cb*16+quad*4+r, q=l15
  float* Ob = Opart + ((size_t)sp * Bb + b) * (size_t)Cc * Nn;
  const int qn = q0 + w * 16 + l15;
#pragma unroll
  for (int cb = 0; cb < 16; ++cb) {
#pragma unroll
    for (int r = 0; r < 4; ++r)
      Ob[(size_t)(cb * 16 + quad * 4 + r) * Nn + qn] = o[cb][r];
  }
  if (lane < 16) {   // quad 0 holds the same (m,l) as all quads
    float* mlb = Ml + ((size_t)sp * Bb + b) * (size_t)Nn * 2;
    *(f32x2*)(mlb + (size_t)qn * 2) = (f32x2){mrow, lrow};
  }
}

// ---------------------------------------------------------------------------
// Merge the KSPLIT K-split partials.
// ---------------------------------------------------------------------------
__global__ void merge_kernel(const float* __restrict__ Opart,
                             const float* __restrict__ Ml,
                             float* __restrict__ out)
{
  const int idx = blockIdx.x * 256 + threadIdx.x;
  const int n4 = idx % 576;
  const int bc = idx / 576;
  const int b  = bc >> 8;
  const size_t o0off = (size_t)bc * Nn + n4 * 4;
  const size_t ostride = (size_t)Bb * Cc * Nn;

  f32x4 ov[KSPLIT];
  float mv[KSPLIT][4], lv[KSPLIT][4];
#pragma unroll
  for (int s = 0; s < KSPLIT; ++s) {
    ov[s] = *(const f32x4*)(Opart + o0off + (size_t)s * ostride);
    const float* ml = Ml + ((size_t)s * Bb + b) * (size_t)Nn * 2 + n4 * 8;
    const f32x4 u0 = *(const f32x4*)ml;
    const f32x4 u1 = *(const f32x4*)(ml + 4);
#pragma unroll
    for (int j = 0; j < 4; ++j) {
      mv[s][j] = (j < 2) ? u0[j * 2]     : u1[(j - 2) * 2];
      lv[s][j] = (j < 2) ? u0[j * 2 + 1] : u1[(j - 2) * 2 + 1];
    }
  }

  f32x4 r;
#pragma unroll
  for (int j = 0; j < 4; ++j) {
    float m = mv[0][j];
#pragma unroll
    for (int s = 1; s < KSPLIT; ++s) m = fmaxf(m, mv[s][j]);
    float num = 0.f, den = 0.f;
#pragma unroll
    for (int s = 0; s < KSPLIT; ++s) {
      const float ws = exp2f((mv[s][j] - m) * L2E);
      num += ov[s][j] * ws;
      den += lv[s][j] * ws;
    }
    r[j] = num / den;
  }
  *(f32x4*)(out + o0off) = r;
}

extern "C" void kernel_launch(void* const* d_in, const int* in_sizes, int n_in,
                              void* d_out, int out_size, void* d_ws, size_t ws_size,
                              hipStream_t stream) {
  const float* x  = (const float*)d_in[0];
  const float* y  = (const float*)d_in[1];
  const float* Wq = (const float*)d_in[2];
  const float* bq = (const float*)d_in[3];
  const float* Wk = (const float*)d_in[4];
  const float* bk = (const float*)d_in[5];
  const float* Wv = (const float*)d_in[6];
  const float* bv = (const float*)d_in[7];
  float* out = (float*)d_out;

  const size_t NC = (size_t)Bb * Nn * Cc;   // 4,718,592
  u16* Qf = (u16*)d_ws;
  u16* Kf = Qf + NC;
  u16* Vf = Kf + NC;
  u16* Wf = Vf + NC;
  float* Opart = (float*)(Wf + 3 * 65536);
  float* Ml    = Opart + (size_t)KSPLIT * NC;

  hipLaunchKernelGGL(prep_kernel, dim3(96), dim3(256), 0, stream,
                     Wq, Wk, Wv, Wf);
  hipLaunchKernelGGL(proj_kernel, dim3(Bb, PQT, 3), dim3(256), 0, stream,
                     x, y, Wf, bq, bk, bv, Qf, Kf, Vf);
  hipLaunchKernelGGL(attn_kernel, dim3(Bb, QTILES, KSPLIT), dim3(256), 0, stream,
                     Qf, Kf, Vf, Opart, Ml);
  hipLaunchKernelGGL(merge_kernel, dim3(4608), dim3(256), 0, stream,
                     Opart, Ml, out);
}